// Round 13
// baseline (90.258 us; speedup 1.0000x reference)
//
#include <hip/hip_runtime.h>
#include <hip/hip_bf16.h>
#include <math.h>

#define B_ 2
#define L_ 1024
#define D_ 1024
#define H_ 16
#define DH_ 64
#define M_ 64
#define R_ 129
#define NLD ((size_t)B_ * L_ * D_)          // 2,097,152
#define DD  ((size_t)D_ * D_)
#define QSCALE 0.18033688011112042f         // DH^-0.5 * log2(e)

using bf16x8 = __attribute__((ext_vector_type(8))) short;
using bf16x4 = __attribute__((ext_vector_type(4))) short;
using f32x4  = __attribute__((ext_vector_type(4))) float;

__device__ __forceinline__ unsigned short f2bf(float f) {
    unsigned int x = __builtin_bit_cast(unsigned int, f);
    unsigned int r = x + 0x7fffu + ((x >> 16) & 1u);   // RNE
    return (unsigned short)(r >> 16);
}
__device__ __forceinline__ float bf2f(unsigned short u) {
    unsigned int x = ((unsigned int)u) << 16;
    return __builtin_bit_cast(float, x);
}
__device__ __forceinline__ unsigned int pk2bf(float lo, float hi) {
    __hip_bfloat162 h = __float22bfloat162_rn(float2{lo, hi});  // v_cvt_pk_bf16_f32 (RNE)
    unsigned int u;
    __builtin_memcpy(&u, &h, 4);
    return u;
}
__device__ __forceinline__ bf16x4 mkbf4(float a, float b, float c, float d) {
    unsigned long long v = (unsigned long long)pk2bf(a, b)
                         | ((unsigned long long)pk2bf(c, d) << 32);
    return __builtin_bit_cast(bf16x4, v);
}
// K=16 MFMA (ISA §10: v_mfma_f32_16x16x16_bf16, A/B 2 VGPRs, C/D 4)
__device__ __forceinline__ f32x4 mfma16(bf16x4 a, bf16x4 b, f32x4 c) {
    asm("v_mfma_f32_16x16x16_bf16 %0, %1, %2, %0" : "+v"(c) : "v"(a), "v"(b));
    return c;
}

// ------------------------------------------------------------------
// prep: [0,2048) x->bf16 | [2048,6144) W transposes | [6144,6180) rel tables
// ------------------------------------------------------------------
__global__ __launch_bounds__(256)
void prep(const float* __restrict__ x,
          const float* __restrict__ W0, const float* __restrict__ W1,
          const float* __restrict__ W2, const float* __restrict__ W3,
          const float* __restrict__ relk, const float* __restrict__ relv,
          unsigned short* __restrict__ xb, unsigned short* __restrict__ Wt,
          unsigned short* __restrict__ relkb, unsigned short* __restrict__ relvT)
{
    __shared__ float tile[32][33];
    const int bid = blockIdx.x, t = threadIdx.x;
    if (bid < 2048) {
        const int i = bid * 256 + t;
        float4 v = ((const float4*)x)[i];
        short4 o = { (short)f2bf(v.x), (short)f2bf(v.y), (short)f2bf(v.z), (short)f2bf(v.w) };
        ((short4*)xb)[i] = o;
    } else if (bid < 6144) {
        const int wb = bid - 2048;
        const int z = wb >> 10, rem = wb & 1023;
        const float* W = z == 0 ? W0 : z == 1 ? W1 : z == 2 ? W2 : W3;
        unsigned short* T = Wt + (size_t)z * DD;
        const int k0 = (rem >> 5) * 32, n0 = (rem & 31) * 32;
        const int r = t >> 3, c = (t & 7) * 4;
        float4 v = *(const float4*)&W[(size_t)(k0 + r) * D_ + n0 + c];
        tile[r][c] = v.x; tile[r][c + 1] = v.y; tile[r][c + 2] = v.z; tile[r][c + 3] = v.w;
        __syncthreads();
        short4 o = { (short)f2bf(tile[c][r]),     (short)f2bf(tile[c + 1][r]),
                     (short)f2bf(tile[c + 2][r]), (short)f2bf(tile[c + 3][r]) };
        *(short4*)&T[(size_t)(n0 + r) * D_ + k0 + c] = o;
    } else {
        const int idx = (bid - 6144) * 256 + t;
        if (idx < 144 * 64) {
            const int r = idx >> 6, d = idx & 63;
            relkb[idx] = (r < R_) ? f2bf(relk[r * 64 + d]) : (unsigned short)0;
        }
        if (idx < 64 * 136) {
            const int d = idx / 136, r = idx - d * 136;
            relvT[idx] = (r < R_) ? f2bf(relv[r * 64 + d]) : (unsigned short)0;
        }
    }
}

// ------------------------------------------------------------------
// 64(M)x128(N)-tile bf16 MFMA GEMM, BK=64, 4 waves x 32x64. (unchanged)
// ------------------------------------------------------------------
__global__ __launch_bounds__(256)
void gemm64(const unsigned short* __restrict__ A, const unsigned short* __restrict__ Bt,
            unsigned short* __restrict__ Cb, float* __restrict__ Cf, float scale0)
{
    __shared__ unsigned short As[64][64];
    __shared__ unsigned short Bs[128][64];

    const int t = threadIdx.x, lane = t & 63, wid = t >> 6;
    const int fr = lane & 15, g = lane >> 4;
    const int m0 = blockIdx.y * 64;
    const int nglob = blockIdx.x * 128;
    const int mat = nglob >> 10;
    const int n0 = nglob & 1023;
    const float scale = (mat == 0) ? scale0 : 1.f;
    const int wm = (wid >> 1) * 32, wn = (wid & 1) * 64;

    f32x4 acc[2][4] = {};

    int arow[2], akof[2], adst[2];
#pragma unroll
    for (int c = 0; c < 2; ++c) {
        const int chunk = c * 256 + t;
        arow[c] = chunk >> 3;
        akof[c] = ((chunk & 7) ^ (arow[c] & 7)) * 8;
        adst[c] = chunk * 8;
    }
    int brow[4], bkof[4], bdst[4];
#pragma unroll
    for (int c = 0; c < 4; ++c) {
        const int chunk = c * 256 + t;
        brow[c] = chunk >> 3;
        bkof[c] = ((chunk & 7) ^ (brow[c] & 7)) * 8;
        bdst[c] = chunk * 8;
    }

    const unsigned short* Abase = A  + (size_t)m0 * D_;
    const unsigned short* Bbase = Bt + (size_t)nglob * D_;

    for (int k0 = 0; k0 < D_; k0 += 64) {
        __syncthreads();
#pragma unroll
        for (int c = 0; c < 2; ++c)
            __builtin_amdgcn_global_load_lds(
                (const __attribute__((address_space(1))) void*)(Abase + (size_t)arow[c] * D_ + k0 + akof[c]),
                (__attribute__((address_space(3))) void*)(&As[0][0] + adst[c]), 16, 0, 0);
#pragma unroll
        for (int c = 0; c < 4; ++c)
            __builtin_amdgcn_global_load_lds(
                (const __attribute__((address_space(1))) void*)(Bbase + (size_t)brow[c] * D_ + k0 + bkof[c]),
                (__attribute__((address_space(3))) void*)(&Bs[0][0] + bdst[c]), 16, 0, 0);
        __syncthreads();

#pragma unroll
        for (int kb = 0; kb < 2; ++kb) {
            bf16x8 av[2], bv[4];
#pragma unroll
            for (int i = 0; i < 2; ++i) {
                const int ra = wm + i * 16 + fr;
                av[i] = *(const bf16x8*)&As[ra][(((kb << 2) + g) ^ (ra & 7)) * 8];
            }
#pragma unroll
            for (int j = 0; j < 4; ++j) {
                const int rb = wn + j * 16 + fr;
                bv[j] = *(const bf16x8*)&Bs[rb][(((kb << 2) + g) ^ (rb & 7)) * 8];
            }
#pragma unroll
            for (int i = 0; i < 2; ++i)
#pragma unroll
                for (int j = 0; j < 4; ++j)
                    acc[i][j] = __builtin_amdgcn_mfma_f32_16x16x32_bf16(av[i], bv[j], acc[i][j], 0, 0, 0);
        }
    }

    const int orow = g * 4;
    if (Cb) {
        unsigned short* Cp = Cb + (size_t)mat * NLD;
#pragma unroll
        for (int i = 0; i < 2; ++i)
#pragma unroll
            for (int j = 0; j < 4; ++j) {
                unsigned short* cp = Cp + (size_t)(m0 + wm + i * 16 + orow) * D_ + n0 + wn + j * 16 + fr;
#pragma unroll
                for (int rg = 0; rg < 4; ++rg)
                    cp[(size_t)rg * D_] = f2bf(acc[i][j][rg] * scale);
            }
    } else {
#pragma unroll
        for (int i = 0; i < 2; ++i)
#pragma unroll
            for (int j = 0; j < 4; ++j) {
                float* cp = Cf + (size_t)(m0 + wm + i * 16 + orow) * D_ + n0 + wn + j * 16 + fr;
#pragma unroll
                for (int rg = 0; rg < 4; ++rg)
                    cp[(size_t)rg * D_] = acc[i][j][rg] * scale;
            }
    }
}

// ------------------------------------------------------------------
// MFMA flash attention, j-partitioned: wave w owns j-window w*16 of each
// 64-tile; all waves hold all 4 row-groups' Q frags. K/V tiles read from
// LDS exactly ONCE per block per tile; P stays in registers (16x16x16 PV).
// ------------------------------------------------------------------
__device__ __forceinline__ void stage_k(const unsigned short* src, unsigned short* dst, int t)
{
#pragma unroll
    for (int it = 0; it < 2; ++it) {
        const int c = it * 256 + t;
        const int j = c >> 3;
        const int sc = (c & 7) ^ (j & 7);
        __builtin_amdgcn_global_load_lds(
            (const __attribute__((address_space(1))) void*)(src + (size_t)j * D_ + sc * 8),
            (__attribute__((address_space(3))) void*)(dst + c * 8), 16, 0, 0);
    }
}

__device__ __forceinline__ void write_vt(unsigned short (*Vtl)[64], int jp, int d0, bf16x8 a, bf16x8 b)
{
    const int jlo = (2 * jp) & 7;
    const int jc  = jp >> 2;
#pragma unroll
    for (int e = 0; e < 8; ++e) {
        const int d = d0 + e;
        const unsigned int val = (unsigned int)(unsigned short)a[e]
                               | ((unsigned int)(unsigned short)b[e] << 16);
        *(unsigned int*)&Vtl[d][((jc ^ (d & 7)) << 3) + jlo] = val;
    }
}

__global__ __launch_bounds__(256, 2)
void attn_mfma(const unsigned short* __restrict__ Qb, const unsigned short* __restrict__ Kb,
               const unsigned short* __restrict__ Vb,
               const unsigned short* __restrict__ relkb,   // [144][64] bf16
               const unsigned short* __restrict__ relvT,   // [64][136] bf16
               const float* __restrict__ relv,             // [129][64] f32
               unsigned short* __restrict__ Ob)
{
    __shared__ __align__(16) unsigned short Klds[3][64][64];  // 24 KB; epilogue scratch
    __shared__ __align__(16) unsigned short Vt[2][64][64];    // 16 KB
    __shared__ unsigned short QW[64][136];                    // 17 KB (QR -> wsum in place)
    __shared__ float lredL[4][4][16], lredP0[4][4][16], lredP128[4][4][16];  // 3 KB

    const int t    = threadIdx.x;
    const int lane = t & 63;
    const int w    = t >> 6;        // j-window owner; also fd-owner in epilogue
    const int fr   = lane & 15;
    const int g    = lane >> 4;

    const int bx  = blockIdx.x;
    const int xcd = bx & 7, slot = bx >> 3;
    const int bh  = (xcd << 2) | (slot >> 4);
    const int rb  = slot & 15;
    const int b   = bh >> 4, h = bh & 15;
    const int i0  = rb * 64;
    const size_t head = (size_t)b * L_ * D_ + (size_t)h * DH_;

    const unsigned short* Kh = Kb + head;
    const unsigned short* Vh = Vb + head;

    // prologue: K[0], K[1] DMA; V[0] via explicit asm loads
    stage_k(Kh, &Klds[0][0][0], t);
    stage_k(Kh + (size_t)64 * D_, &Klds[1][0][0], t);

    const int jp = t & 31, d0v = ((t >> 5) & 7) * 8;
    bf16x8 va, vb2;
    {
        const unsigned short* vsrc = Vh + (size_t)(2 * jp) * D_ + d0v;
        asm volatile("global_load_dwordx4 %0, %1, off" : "=v"(va)  : "v"(vsrc)      : "memory");
        asm volatile("global_load_dwordx4 %0, %1, off" : "=v"(vb2) : "v"(vsrc + D_) : "memory");
    }

    // Q fragments for ALL 4 row-groups: qf[c][kb] = Q[i0+c*16+fr][kb*32+g*8..]
    bf16x8 qf[4][2];
#pragma unroll
    for (int c = 0; c < 4; ++c) {
        const unsigned short* qp = Qb + head + (size_t)(i0 + c * 16 + fr) * D_;
        qf[c][0] = *(const bf16x8*)(qp + g * 8);
        qf[c][1] = *(const bf16x8*)(qp + 32 + g * 8);
    }

    // QR: rc blocks split across waves; D[col=qrow c*16+fr][row r=rc*16+g*4+reg]
    auto qr_rc = [&](int rc) {
#pragma unroll
        for (int c = 0; c < 4; ++c) {
            f32x4 acc = {};
#pragma unroll
            for (int kb = 0; kb < 2; ++kb) {
                bf16x8 rv = *(const bf16x8*)&relkb[(size_t)(rc * 16 + fr) * 64 + kb * 32 + g * 8];
                acc = __builtin_amdgcn_mfma_f32_16x16x32_bf16(rv, qf[c][kb], acc, 0, 0, 0);
            }
            if (rc < 8) {
                unsigned long long pk = (unsigned long long)pk2bf(acc[0], acc[1])
                                      | ((unsigned long long)pk2bf(acc[2], acc[3]) << 32);
                *(unsigned long long*)&QW[c * 16 + fr][rc * 16 + g * 4] = pk;
            } else if (g == 0) {
                QW[c * 16 + fr][128] = f2bf(acc[0]);
            }
        }
    };
    if      (w == 0) { qr_rc(0); qr_rc(4); qr_rc(8); }
    else if (w == 1) { qr_rc(1); qr_rc(5); }
    else if (w == 2) { qr_rc(2); qr_rc(6); }
    else             { qr_rc(3); qr_rc(7); }

    __syncthreads();   // QR table complete

    // zero stale interior cols (boundary blocks); wave handles rows w*16+fr
    {
        const int zrow = w * 16 + fr;
        if (rb == 0) {
            for (int c = 1 + g; c <= 63 - zrow; c += 4) QW[zrow][c] = 0;
        } else if (rb == 15) {
            for (int c = 128 - zrow + g; c <= 127; c += 4) QW[zrow][c] = 0;
        }
    }
    float qr0[4], qr128[4];
#pragma unroll
    for (int c = 0; c < 4; ++c) {
        qr0[c]   = bf2f(QW[c * 16 + fr][0]);
        qr128[c] = bf2f(QW[c * 16 + fr][128]);
    }

    asm volatile("s_waitcnt vmcnt(0)" ::: "memory");   // V[0], K[0..1] landed
    __builtin_amdgcn_sched_barrier(0);
    write_vt(Vt[0], jp, d0v, va, vb2);
    __syncthreads();

    f32x4 oacc[4][4] = {};                // [fd][c], partial over this wave's j
    float lpart[4] = {}, pe0p[4] = {}, pe128p[4] = {};

    int kcur = 0;
    for (int jt = 0; jt < 16; ++jt) {
        if (jt < 15) {
            const unsigned short* vsrc = Vh + (size_t)((jt + 1) * 64 + 2 * jp) * D_ + d0v;
            asm volatile("global_load_dwordx4 %0, %1, off" : "=v"(va)  : "v"(vsrc)      : "memory");
            asm volatile("global_load_dwordx4 %0, %1, off" : "=v"(vb2) : "v"(vsrc + D_) : "memory");
        }
        if (jt < 14) {
            int kpre = kcur + 2; if (kpre >= 3) kpre -= 3;
            stage_k(Kh + (size_t)(jt + 2) * 64 * D_, &Klds[kpre][0][0], t);
        }

        // ---- S^T = K @ Q^T over this wave's 16-j window (j = w*16+fr rows) ----
        const int jrow = w * 16 + fr;
        bf16x8 kv0 = *(const bf16x8*)&Klds[kcur][jrow][((g)     ^ (fr & 7)) * 8];
        bf16x8 kv1 = *(const bf16x8*)&Klds[kcur][jrow][((4 + g) ^ (fr & 7)) * 8];
        // V^T A-frags (b64): d = fd*16+fr, j = w*16+g*4..+3
        bf16x4 vt4[4];
#pragma unroll
        for (int fd = 0; fd < 4; ++fd) {
            const int d = fd * 16 + fr;
            vt4[fd] = *(const bf16x4*)&Vt[jt & 1][d][((((w << 1) + (g >> 1)) ^ (d & 7)) << 3) + (g & 1) * 4];
        }

        f32x4 s[4];
        __builtin_amdgcn_s_setprio(1);
#pragma unroll
        for (int c = 0; c < 4; ++c) {
            f32x4 a = {};
            a = __builtin_amdgcn_mfma_f32_16x16x32_bf16(kv0, qf[c][0], a, 0, 0, 0);
            a = __builtin_amdgcn_mfma_f32_16x16x32_bf16(kv1, qf[c][1], a, 0, 0, 0);
            s[c] = a;   // s[c][reg] = S[qrow=c*16+fr][j = jt*64 + w*16 + g*4+reg]
        }
        __builtin_amdgcn_s_setprio(0);

        // ---- softmax; P stays in registers as PV B-frags ----
        const int base_u = (jt - rb) * 64 + w * 16;
        bf16x4 pb[4];
#pragma unroll
        for (int c = 0; c < 4; ++c) {
            const int u   = base_u - c * 16;
            const int row = c * 16 + fr;
            float p0, p1, p2, p3;
            if (u <= -80 || u >= 80) {
                const float qrc = (u < 0) ? qr0[c] : qr128[c];
                p0 = exp2f(s[c][0] + qrc); p1 = exp2f(s[c][1] + qrc);
                p2 = exp2f(s[c][2] + qrc); p3 = exp2f(s[c][3] + qrc);
                const float ts = (p0 + p1) + (p2 + p3);
                lpart[c] += ts;
                if (u < 0) pe0p[c] += ts; else pe128p[c] += ts;
            } else if (u >= -48 && u <= 48) {
                const int cb = u + 64 - fr + g * 4;   // in [1,124]
                p0 = exp2f(s[c][0] + bf2f(QW[row][cb]));
                p1 = exp2f(s[c][1] + bf2f(QW[row][cb + 1]));
                p2 = exp2f(s[c][2] + bf2f(QW[row][cb + 2]));
                p3 = exp2f(s[c][3] + bf2f(QW[row][cb + 3]));
                lpart[c] += (p0 + p1) + (p2 + p3);
                QW[row][cb]     = f2bf(p0);
                QW[row][cb + 1] = f2bf(p1);
                QW[row][cb + 2] = f2bf(p2);
                QW[row][cb + 3] = f2bf(p3);
            } else {
                // EDGE: u == +-64
                float pe[4];
#pragma unroll
                for (int e = 0; e < 4; ++e) {
                    const int colr = u + 64 - fr + g * 4 + e;
                    const int col  = colr < 0 ? 0 : (colr > 128 ? 128 : colr);
                    const float bias = (col == 0) ? qr0[c]
                                     : (col == 128) ? qr128[c]
                                     : bf2f(QW[row][col]);
                    pe[e] = exp2f(s[c][e] + bias);
                    lpart[c] += pe[e];
                    if (col == 0)        pe0p[c]   += pe[e];
                    else if (col == 128) pe128p[c] += pe[e];
                    else                 QW[row][col] = f2bf(pe[e]);
                }
                p0 = pe[0]; p1 = pe[1]; p2 = pe[2]; p3 = pe[3];
            }
            pb[c] = mkbf4(p0, p1, p2, p3);
        }

        // ---- PV: 16x16x16, A = V^T frag, B = P (registers) ----
        __builtin_amdgcn_s_setprio(1);
#pragma unroll
        for (int fd = 0; fd < 4; ++fd)
#pragma unroll
            for (int c = 0; c < 4; ++c)
                oacc[fd][c] = mfma16(vt4[fd], pb[c], oacc[fd][c]);
        __builtin_amdgcn_s_setprio(0);

        if (jt < 15) {
            if (jt < 14) asm volatile("s_waitcnt vmcnt(2)" ::: "memory");
            else         asm volatile("s_waitcnt vmcnt(0)" ::: "memory");
            __builtin_amdgcn_sched_barrier(0);
            write_vt(Vt[(jt + 1) & 1], jp, d0v, va, vb2);
        }
        asm volatile("s_waitcnt lgkmcnt(0)" ::: "memory");
        __builtin_amdgcn_s_barrier();
        kcur = (kcur == 2) ? 0 : kcur + 1;
    }

    // ---- reduce row partials: over g (shfl), then over waves (LDS) ----
#pragma unroll
    for (int c = 0; c < 4; ++c) {
        lpart[c]  += __shfl_xor(lpart[c], 16);  lpart[c]  += __shfl_xor(lpart[c], 32);
        pe0p[c]   += __shfl_xor(pe0p[c], 16);   pe0p[c]   += __shfl_xor(pe0p[c], 32);
        pe128p[c] += __shfl_xor(pe128p[c], 16); pe128p[c] += __shfl_xor(pe128p[c], 32);
    }
    if (lane < 16) {
#pragma unroll
        for (int c = 0; c < 4; ++c) {
            lredL[w][c][fr]   = lpart[c];
            lredP0[w][c][fr]  = pe0p[c];
            lredP128[w][c][fr]= pe128p[c];
        }
    }
    __syncthreads();
    float lt[4], p0t[4], p128t[4];
#pragma unroll
    for (int c = 0; c < 4; ++c) {
        lt[c]    = (lredL[0][c][fr] + lredL[1][c][fr]) + (lredL[2][c][fr] + lredL[3][c][fr]);
        p0t[c]   = (lredP0[0][c][fr] + lredP0[1][c][fr]) + (lredP0[2][c][fr] + lredP0[3][c][fr]);
        p128t[c] = (lredP128[0][c][fr] + lredP128[1][c][fr]) + (lredP128[2][c][fr] + lredP128[3][c][fr]);
    }
    if (w == 0 && g == 0) {
#pragma unroll
        for (int c = 0; c < 4; ++c) {
            QW[c * 16 + fr][0]   = f2bf(p0t[c]);
            QW[c * 16 + fr][128] = f2bf(p128t[c]);
        }
    }
    __syncthreads();

    // ---- relv term (once): owner wave adds into its fd=w quarter ----
#pragma unroll
    for (int kc = 0; kc < 4; ++kc) {
        bf16x8 rv = *(const bf16x8*)&relvT[(size_t)(w * 16 + fr) * 136 + kc * 32 + g * 8];
#pragma unroll
        for (int c = 0; c < 4; ++c) {
            bf16x8 wa = *(const bf16x8*)&QW[c * 16 + fr][kc * 32 + g * 8];
            oacc[w][c] = __builtin_amdgcn_mfma_f32_16x16x32_bf16(rv, wa, oacc[w][c], 0, 0, 0);
        }
    }

    // ---- O cross-wave reduction (scratch = Klds), fd round-robin ----
    float* scr = (float*)&Klds[0][0][0];   // need 12 KB of the 24
    for (int fd = 0; fd < 4; ++fd) {
        if (w != fd) {
            const int sI = w - (w > fd ? 1 : 0);
#pragma unroll
            for (int c = 0; c < 4; ++c)
                *(f32x4*)&scr[(sI * 4 + c) * 256 + lane * 4] = oacc[fd][c];
        }
        __syncthreads();
        if (w == fd) {
#pragma unroll
            for (int c = 0; c < 4; ++c)
#pragma unroll
                for (int sI = 0; sI < 3; ++sI)
                    oacc[fd][c] += *(const f32x4*)&scr[(sI * 4 + c) * 256 + lane * 4];
        }
        __syncthreads();
    }

    // ---- owner wave writes its d-quarter for all 64 rows ----
    float r128[4];
#pragma unroll
    for (int reg = 0; reg < 4; ++reg)
        r128[reg] = relv[128 * 64 + w * 16 + g * 4 + reg];
#pragma unroll
    for (int c = 0; c < 4; ++c) {
        const float inv = 1.f / lt[c];
        float v0 = (oacc[w][c][0] + p128t[c] * r128[0]) * inv;
        float v1 = (oacc[w][c][1] + p128t[c] * r128[1]) * inv;
        float v2 = (oacc[w][c][2] + p128t[c] * r128[2]) * inv;
        float v3 = (oacc[w][c][3] + p128t[c] * r128[3]) * inv;
        unsigned long long pk = (unsigned long long)pk2bf(v0, v1)
                              | ((unsigned long long)pk2bf(v2, v3) << 32);
        *(unsigned long long*)&Ob[head + (size_t)(i0 + c * 16 + fr) * D_ + w * 16 + g * 4] = pk;
    }
}

// ------------------------------------------------------------------
extern "C" void kernel_launch(void* const* d_in, const int* in_sizes, int n_in,
                              void* d_out, int out_size, void* d_ws, size_t ws_size,
                              hipStream_t stream)
{
    const float* x    = (const float*)d_in[0];
    const float* Wq   = (const float*)d_in[1];
    const float* Wk   = (const float*)d_in[2];
    const float* Wv   = (const float*)d_in[3];
    const float* Wo   = (const float*)d_in[4];
    const float* relk = (const float*)d_in[5];
    const float* relv = (const float*)d_in[6];
    float* out = (float*)d_out;

    unsigned short* xb    = (unsigned short*)d_ws;
    unsigned short* Wt    = xb + NLD;
    unsigned short* relkb = Wt + 4 * DD;
    unsigned short* relvT = relkb + 144 * 64;
    unsigned short* QKVb  = relvT + 64 * 136;
    unsigned short* Ob    = QKVb + 3 * NLD;

    prep<<<dim3(6180), 256, 0, stream>>>(x, Wq, Wk, Wv, Wo, relk, relv, xb, Wt, relkb, relvT);

    gemm64<<<dim3(24, 32), 256, 0, stream>>>(xb, Wt, QKVb, nullptr, QSCALE);   // Q,K,V fused

    attn_mfma<<<dim3(512), 256, 0, stream>>>(QKVb, QKVb + NLD, QKVb + 2 * NLD,
                                             relkb, relvT, relv, Ob);

    gemm64<<<dim3(8, 32), 256, 0, stream>>>(Ob, Wt + 3 * DD, nullptr, out, 1.f);
}

// Round 14
// 89.165 us; speedup vs baseline: 1.0123x; 1.0123x over previous
//
#include <hip/hip_runtime.h>
#include <hip/hip_bf16.h>
#include <math.h>

#define B_ 2
#define L_ 1024
#define D_ 1024
#define H_ 16
#define DH_ 64
#define M_ 64
#define R_ 129
#define NLD ((size_t)B_ * L_ * D_)          // 2,097,152
#define DD  ((size_t)D_ * D_)
#define QSCALE 0.18033688011112042f         // DH^-0.5 * log2(e)

using bf16x8 = __attribute__((ext_vector_type(8))) short;
using bf16x4 = __attribute__((ext_vector_type(4))) short;
using f32x4  = __attribute__((ext_vector_type(4))) float;

__device__ __forceinline__ unsigned short f2bf(float f) {
    unsigned int x = __builtin_bit_cast(unsigned int, f);
    unsigned int r = x + 0x7fffu + ((x >> 16) & 1u);   // RNE
    return (unsigned short)(r >> 16);
}
__device__ __forceinline__ float bf2f(unsigned short u) {
    unsigned int x = ((unsigned int)u) << 16;
    return __builtin_bit_cast(float, x);
}
__device__ __forceinline__ unsigned int pk2bf(float lo, float hi) {
    __hip_bfloat162 h = __float22bfloat162_rn(float2{lo, hi});  // v_cvt_pk_bf16_f32 (RNE)
    unsigned int u;
    __builtin_memcpy(&u, &h, 4);
    return u;
}
__device__ __forceinline__ bf16x4 mkbf4(float a, float b, float c, float d) {
    unsigned long long v = (unsigned long long)pk2bf(a, b)
                         | ((unsigned long long)pk2bf(c, d) << 32);
    return __builtin_bit_cast(bf16x4, v);
}
// K=16 MFMA (ISA §10: v_mfma_f32_16x16x16_bf16, A/B 2 VGPRs, C/D 4)
__device__ __forceinline__ f32x4 mfma16(bf16x4 a, bf16x4 b, f32x4 c) {
    asm("v_mfma_f32_16x16x16_bf16 %0, %1, %2, %0" : "+v"(c) : "v"(a), "v"(b));
    return c;
}

// ------------------------------------------------------------------
// prep: [0,2048) x->bf16 | [2048,6144) W transposes | [6144,6180) rel tables
// ------------------------------------------------------------------
__global__ __launch_bounds__(256)
void prep(const float* __restrict__ x,
          const float* __restrict__ W0, const float* __restrict__ W1,
          const float* __restrict__ W2, const float* __restrict__ W3,
          const float* __restrict__ relk, const float* __restrict__ relv,
          unsigned short* __restrict__ xb, unsigned short* __restrict__ Wt,
          unsigned short* __restrict__ relkb, unsigned short* __restrict__ relvT)
{
    __shared__ float tile[32][33];
    const int bid = blockIdx.x, t = threadIdx.x;
    if (bid < 2048) {
        const int i = bid * 256 + t;
        float4 v = ((const float4*)x)[i];
        short4 o = { (short)f2bf(v.x), (short)f2bf(v.y), (short)f2bf(v.z), (short)f2bf(v.w) };
        ((short4*)xb)[i] = o;
    } else if (bid < 6144) {
        const int wb = bid - 2048;
        const int z = wb >> 10, rem = wb & 1023;
        const float* W = z == 0 ? W0 : z == 1 ? W1 : z == 2 ? W2 : W3;
        unsigned short* T = Wt + (size_t)z * DD;
        const int k0 = (rem >> 5) * 32, n0 = (rem & 31) * 32;
        const int r = t >> 3, c = (t & 7) * 4;
        float4 v = *(const float4*)&W[(size_t)(k0 + r) * D_ + n0 + c];
        tile[r][c] = v.x; tile[r][c + 1] = v.y; tile[r][c + 2] = v.z; tile[r][c + 3] = v.w;
        __syncthreads();
        short4 o = { (short)f2bf(tile[c][r]),     (short)f2bf(tile[c + 1][r]),
                     (short)f2bf(tile[c + 2][r]), (short)f2bf(tile[c + 3][r]) };
        *(short4*)&T[(size_t)(n0 + r) * D_ + k0 + c] = o;
    } else {
        const int idx = (bid - 6144) * 256 + t;
        if (idx < 144 * 64) {
            const int r = idx >> 6, d = idx & 63;
            relkb[idx] = (r < R_) ? f2bf(relk[r * 64 + d]) : (unsigned short)0;
        }
        if (idx < 64 * 136) {
            const int d = idx / 136, r = idx - d * 136;
            relvT[idx] = (r < R_) ? f2bf(relv[r * 64 + d]) : (unsigned short)0;
        }
    }
}

// ------------------------------------------------------------------
// 64(M)x128(N)-tile bf16 MFMA GEMM, BK=64, 4 waves x 32x64. (unchanged)
// ------------------------------------------------------------------
__global__ __launch_bounds__(256)
void gemm64(const unsigned short* __restrict__ A, const unsigned short* __restrict__ Bt,
            unsigned short* __restrict__ Cb, float* __restrict__ Cf, float scale0)
{
    __shared__ unsigned short As[64][64];
    __shared__ unsigned short Bs[128][64];

    const int t = threadIdx.x, lane = t & 63, wid = t >> 6;
    const int fr = lane & 15, g = lane >> 4;
    const int m0 = blockIdx.y * 64;
    const int nglob = blockIdx.x * 128;
    const int mat = nglob >> 10;
    const int n0 = nglob & 1023;
    const float scale = (mat == 0) ? scale0 : 1.f;
    const int wm = (wid >> 1) * 32, wn = (wid & 1) * 64;

    f32x4 acc[2][4] = {};

    int arow[2], akof[2], adst[2];
#pragma unroll
    for (int c = 0; c < 2; ++c) {
        const int chunk = c * 256 + t;
        arow[c] = chunk >> 3;
        akof[c] = ((chunk & 7) ^ (arow[c] & 7)) * 8;
        adst[c] = chunk * 8;
    }
    int brow[4], bkof[4], bdst[4];
#pragma unroll
    for (int c = 0; c < 4; ++c) {
        const int chunk = c * 256 + t;
        brow[c] = chunk >> 3;
        bkof[c] = ((chunk & 7) ^ (brow[c] & 7)) * 8;
        bdst[c] = chunk * 8;
    }

    const unsigned short* Abase = A  + (size_t)m0 * D_;
    const unsigned short* Bbase = Bt + (size_t)nglob * D_;

    for (int k0 = 0; k0 < D_; k0 += 64) {
        __syncthreads();
#pragma unroll
        for (int c = 0; c < 2; ++c)
            __builtin_amdgcn_global_load_lds(
                (const __attribute__((address_space(1))) void*)(Abase + (size_t)arow[c] * D_ + k0 + akof[c]),
                (__attribute__((address_space(3))) void*)(&As[0][0] + adst[c]), 16, 0, 0);
#pragma unroll
        for (int c = 0; c < 4; ++c)
            __builtin_amdgcn_global_load_lds(
                (const __attribute__((address_space(1))) void*)(Bbase + (size_t)brow[c] * D_ + k0 + bkof[c]),
                (__attribute__((address_space(3))) void*)(&Bs[0][0] + bdst[c]), 16, 0, 0);
        __syncthreads();

#pragma unroll
        for (int kb = 0; kb < 2; ++kb) {
            bf16x8 av[2], bv[4];
#pragma unroll
            for (int i = 0; i < 2; ++i) {
                const int ra = wm + i * 16 + fr;
                av[i] = *(const bf16x8*)&As[ra][(((kb << 2) + g) ^ (ra & 7)) * 8];
            }
#pragma unroll
            for (int j = 0; j < 4; ++j) {
                const int rb = wn + j * 16 + fr;
                bv[j] = *(const bf16x8*)&Bs[rb][(((kb << 2) + g) ^ (rb & 7)) * 8];
            }
#pragma unroll
            for (int i = 0; i < 2; ++i)
#pragma unroll
                for (int j = 0; j < 4; ++j)
                    acc[i][j] = __builtin_amdgcn_mfma_f32_16x16x32_bf16(av[i], bv[j], acc[i][j], 0, 0, 0);
        }
    }

    const int orow = g * 4;
    if (Cb) {
        unsigned short* Cp = Cb + (size_t)mat * NLD;
#pragma unroll
        for (int i = 0; i < 2; ++i)
#pragma unroll
            for (int j = 0; j < 4; ++j) {
                unsigned short* cp = Cp + (size_t)(m0 + wm + i * 16 + orow) * D_ + n0 + wn + j * 16 + fr;
#pragma unroll
                for (int rg = 0; rg < 4; ++rg)
                    cp[(size_t)rg * D_] = f2bf(acc[i][j][rg] * scale);
            }
    } else {
#pragma unroll
        for (int i = 0; i < 2; ++i)
#pragma unroll
            for (int j = 0; j < 4; ++j) {
                float* cp = Cf + (size_t)(m0 + wm + i * 16 + orow) * D_ + n0 + wn + j * 16 + fr;
#pragma unroll
                for (int rg = 0; rg < 4; ++rg)
                    cp[(size_t)rg * D_] = acc[i][j][rg] * scale;
            }
    }
}

// ------------------------------------------------------------------
// MFMA flash attention, j-partitioned: wave w owns j-window w*16 of each
// 64-tile; all waves hold all 4 row-groups' Q frags. K/V tiles read from
// LDS exactly ONCE per block per tile; P stays in registers (16x16x16 PV).
// ------------------------------------------------------------------
__device__ __forceinline__ void stage_k(const unsigned short* src, unsigned short* dst, int t)
{
#pragma unroll
    for (int it = 0; it < 2; ++it) {
        const int c = it * 256 + t;
        const int j = c >> 3;
        const int sc = (c & 7) ^ (j & 7);
        __builtin_amdgcn_global_load_lds(
            (const __attribute__((address_space(1))) void*)(src + (size_t)j * D_ + sc * 8),
            (__attribute__((address_space(3))) void*)(dst + c * 8), 16, 0, 0);
    }
}

__device__ __forceinline__ void write_vt(unsigned short (*Vtl)[64], int jp, int d0, bf16x8 a, bf16x8 b)
{
    const int jlo = (2 * jp) & 7;
    const int jc  = jp >> 2;
#pragma unroll
    for (int e = 0; e < 8; ++e) {
        const int d = d0 + e;
        const unsigned int val = (unsigned int)(unsigned short)a[e]
                               | ((unsigned int)(unsigned short)b[e] << 16);
        *(unsigned int*)&Vtl[d][((jc ^ (d & 7)) << 3) + jlo] = val;
    }
}

__global__ __launch_bounds__(256, 2)
void attn_mfma(const unsigned short* __restrict__ Qb, const unsigned short* __restrict__ Kb,
               const unsigned short* __restrict__ Vb,
               const unsigned short* __restrict__ relkb,   // [144][64] bf16
               const unsigned short* __restrict__ relvT,   // [64][136] bf16
               const float* __restrict__ relv,             // [129][64] f32
               unsigned short* __restrict__ Ob)
{
    __shared__ __align__(16) unsigned short Klds[3][64][64];  // 24 KB; epilogue scratch
    __shared__ __align__(16) unsigned short Vt[2][64][64];    // 16 KB
    __shared__ unsigned short QW[64][136];                    // 17 KB (QR -> wsum in place)
    __shared__ float lredL[4][4][16], lredP0[4][4][16], lredP128[4][4][16];  // 3 KB

    const int t    = threadIdx.x;
    const int lane = t & 63;
    const int w    = t >> 6;        // j-window owner; also fd-owner in epilogue
    const int fr   = lane & 15;
    const int g    = lane >> 4;

    const int bx  = blockIdx.x;
    const int xcd = bx & 7, slot = bx >> 3;
    const int bh  = (xcd << 2) | (slot >> 4);
    const int rb  = slot & 15;
    const int b   = bh >> 4, h = bh & 15;
    const int i0  = rb * 64;
    const size_t head = (size_t)b * L_ * D_ + (size_t)h * DH_;

    const unsigned short* Kh = Kb + head;
    const unsigned short* Vh = Vb + head;

    // prologue: K[0], K[1] DMA; V[0] via explicit asm loads
    stage_k(Kh, &Klds[0][0][0], t);
    stage_k(Kh + (size_t)64 * D_, &Klds[1][0][0], t);

    const int jp = t & 31, d0v = ((t >> 5) & 7) * 8;
    bf16x8 va, vb2;
    {
        const unsigned short* vsrc = Vh + (size_t)(2 * jp) * D_ + d0v;
        asm volatile("global_load_dwordx4 %0, %1, off" : "=v"(va)  : "v"(vsrc)      : "memory");
        asm volatile("global_load_dwordx4 %0, %1, off" : "=v"(vb2) : "v"(vsrc + D_) : "memory");
    }

    // Q fragments for ALL 4 row-groups: qf[c][kb] = Q[i0+c*16+fr][kb*32+g*8..]
    bf16x8 qf[4][2];
#pragma unroll
    for (int c = 0; c < 4; ++c) {
        const unsigned short* qp = Qb + head + (size_t)(i0 + c * 16 + fr) * D_;
        qf[c][0] = *(const bf16x8*)(qp + g * 8);
        qf[c][1] = *(const bf16x8*)(qp + 32 + g * 8);
    }

    // QR: rc blocks split across waves; D[col=qrow c*16+fr][row r=rc*16+g*4+reg]
    auto qr_rc = [&](int rc) {
#pragma unroll
        for (int c = 0; c < 4; ++c) {
            f32x4 acc = {};
#pragma unroll
            for (int kb = 0; kb < 2; ++kb) {
                bf16x8 rv = *(const bf16x8*)&relkb[(size_t)(rc * 16 + fr) * 64 + kb * 32 + g * 8];
                acc = __builtin_amdgcn_mfma_f32_16x16x32_bf16(rv, qf[c][kb], acc, 0, 0, 0);
            }
            if (rc < 8) {
                unsigned long long pk = (unsigned long long)pk2bf(acc[0], acc[1])
                                      | ((unsigned long long)pk2bf(acc[2], acc[3]) << 32);
                *(unsigned long long*)&QW[c * 16 + fr][rc * 16 + g * 4] = pk;
            } else if (g == 0) {
                QW[c * 16 + fr][128] = f2bf(acc[0]);
            }
        }
    };
    if      (w == 0) { qr_rc(0); qr_rc(4); qr_rc(8); }
    else if (w == 1) { qr_rc(1); qr_rc(5); }
    else if (w == 2) { qr_rc(2); qr_rc(6); }
    else             { qr_rc(3); qr_rc(7); }

    __syncthreads();   // QR table complete

    // zero stale interior cols (boundary blocks); wave handles rows w*16+fr
    {
        const int zrow = w * 16 + fr;
        if (rb == 0) {
            for (int c = 1 + g; c <= 63 - zrow; c += 4) QW[zrow][c] = 0;
        } else if (rb == 15) {
            for (int c = 128 - zrow + g; c <= 127; c += 4) QW[zrow][c] = 0;
        }
    }
    float qr0[4], qr128[4];
#pragma unroll
    for (int c = 0; c < 4; ++c) {
        qr0[c]   = bf2f(QW[c * 16 + fr][0]);
        qr128[c] = bf2f(QW[c * 16 + fr][128]);
    }

    asm volatile("s_waitcnt vmcnt(0)" ::: "memory");   // V[0], K[0..1] landed
    __builtin_amdgcn_sched_barrier(0);
    write_vt(Vt[0], jp, d0v, va, vb2);
    __syncthreads();

    f32x4 oacc[4][4] = {};                // [fd][c], partial over this wave's j
    float lpart[4] = {}, pe0p[4] = {}, pe128p[4] = {};

    int kcur = 0;
    for (int jt = 0; jt < 16; ++jt) {
        if (jt < 15) {
            const unsigned short* vsrc = Vh + (size_t)((jt + 1) * 64 + 2 * jp) * D_ + d0v;
            asm volatile("global_load_dwordx4 %0, %1, off" : "=v"(va)  : "v"(vsrc)      : "memory");
            asm volatile("global_load_dwordx4 %0, %1, off" : "=v"(vb2) : "v"(vsrc + D_) : "memory");
        }
        if (jt < 14) {
            int kpre = kcur + 2; if (kpre >= 3) kpre -= 3;
            stage_k(Kh + (size_t)(jt + 2) * 64 * D_, &Klds[kpre][0][0], t);
        }

        // ---- S^T = K @ Q^T over this wave's 16-j window (j = w*16+fr rows) ----
        const int jrow = w * 16 + fr;
        bf16x8 kv0 = *(const bf16x8*)&Klds[kcur][jrow][((g)     ^ (fr & 7)) * 8];
        bf16x8 kv1 = *(const bf16x8*)&Klds[kcur][jrow][((4 + g) ^ (fr & 7)) * 8];
        // V^T A-frags (b64): d = fd*16+fr, j = w*16+g*4..+3
        bf16x4 vt4[4];
#pragma unroll
        for (int fd = 0; fd < 4; ++fd) {
            const int d = fd * 16 + fr;
            vt4[fd] = *(const bf16x4*)&Vt[jt & 1][d][((((w << 1) + (g >> 1)) ^ (d & 7)) << 3) + (g & 1) * 4];
        }

        f32x4 s[4];
        __builtin_amdgcn_s_setprio(1);
#pragma unroll
        for (int c = 0; c < 4; ++c) {
            f32x4 a = {};
            a = __builtin_amdgcn_mfma_f32_16x16x32_bf16(kv0, qf[c][0], a, 0, 0, 0);
            a = __builtin_amdgcn_mfma_f32_16x16x32_bf16(kv1, qf[c][1], a, 0, 0, 0);
            s[c] = a;   // s[c][reg] = S[qrow=c*16+fr][j = jt*64 + w*16 + g*4+reg]
        }
        __builtin_amdgcn_s_setprio(0);

        // ---- softmax; P stays in registers as PV B-frags ----
        const int base_u = (jt - rb) * 64 + w * 16;
        bf16x4 pb[4];
#pragma unroll
        for (int c = 0; c < 4; ++c) {
            const int u   = base_u - c * 16;
            const int row = c * 16 + fr;
            float p0, p1, p2, p3;
            if (u <= -80 || u >= 80) {
                const float qrc = (u < 0) ? qr0[c] : qr128[c];
                p0 = exp2f(s[c][0] + qrc); p1 = exp2f(s[c][1] + qrc);
                p2 = exp2f(s[c][2] + qrc); p3 = exp2f(s[c][3] + qrc);
                const float ts = (p0 + p1) + (p2 + p3);
                lpart[c] += ts;
                if (u < 0) pe0p[c] += ts; else pe128p[c] += ts;
            } else if (u >= -48 && u <= 48) {
                const int cb = u + 64 - fr + g * 4;   // in [1,124]
                p0 = exp2f(s[c][0] + bf2f(QW[row][cb]));
                p1 = exp2f(s[c][1] + bf2f(QW[row][cb + 1]));
                p2 = exp2f(s[c][2] + bf2f(QW[row][cb + 2]));
                p3 = exp2f(s[c][3] + bf2f(QW[row][cb + 3]));
                lpart[c] += (p0 + p1) + (p2 + p3);
                QW[row][cb]     = f2bf(p0);
                QW[row][cb + 1] = f2bf(p1);
                QW[row][cb + 2] = f2bf(p2);
                QW[row][cb + 3] = f2bf(p3);
            } else {
                // EDGE: u == +-64
                float pe[4];
#pragma unroll
                for (int e = 0; e < 4; ++e) {
                    const int colr = u + 64 - fr + g * 4 + e;
                    const int col  = colr < 0 ? 0 : (colr > 128 ? 128 : colr);
                    const float bias = (col == 0) ? qr0[c]
                                     : (col == 128) ? qr128[c]
                                     : bf2f(QW[row][col]);
                    pe[e] = exp2f(s[c][e] + bias);
                    lpart[c] += pe[e];
                    if (col == 0)        pe0p[c]   += pe[e];
                    else if (col == 128) pe128p[c] += pe[e];
                    else                 QW[row][col] = f2bf(pe[e]);
                }
                p0 = pe[0]; p1 = pe[1]; p2 = pe[2]; p3 = pe[3];
            }
            pb[c] = mkbf4(p0, p1, p2, p3);
        }

        // ---- PV: 16x16x16, A = V^T frag, B = P (registers) ----
        __builtin_amdgcn_s_setprio(1);
#pragma unroll
        for (int fd = 0; fd < 4; ++fd)
#pragma unroll
            for (int c = 0; c < 4; ++c)
                oacc[fd][c] = mfma16(vt4[fd], pb[c], oacc[fd][c]);
        __builtin_amdgcn_s_setprio(0);

        if (jt < 15) {
            if (jt < 14) asm volatile("s_waitcnt vmcnt(2)" ::: "memory");
            else         asm volatile("s_waitcnt vmcnt(0)" ::: "memory");
            __builtin_amdgcn_sched_barrier(0);
            write_vt(Vt[(jt + 1) & 1], jp, d0v, va, vb2);
        }
        asm volatile("s_waitcnt lgkmcnt(0)" ::: "memory");
        __builtin_amdgcn_s_barrier();
        kcur = (kcur == 2) ? 0 : kcur + 1;
    }

    // ---- reduce row partials: over g (shfl), then over waves (LDS) ----
#pragma unroll
    for (int c = 0; c < 4; ++c) {
        lpart[c]  += __shfl_xor(lpart[c], 16);  lpart[c]  += __shfl_xor(lpart[c], 32);
        pe0p[c]   += __shfl_xor(pe0p[c], 16);   pe0p[c]   += __shfl_xor(pe0p[c], 32);
        pe128p[c] += __shfl_xor(pe128p[c], 16); pe128p[c] += __shfl_xor(pe128p[c], 32);
    }
    if (lane < 16) {
#pragma unroll
        for (int c = 0; c < 4; ++c) {
            lredL[w][c][fr]   = lpart[c];
            lredP0[w][c][fr]  = pe0p[c];
            lredP128[w][c][fr]= pe128p[c];
        }
    }
    __syncthreads();
    float lt[4], p0t[4], p128t[4];
#pragma unroll
    for (int c = 0; c < 4; ++c) {
        lt[c]    = (lredL[0][c][fr] + lredL[1][c][fr]) + (lredL[2][c][fr] + lredL[3][c][fr]);
        p0t[c]   = (lredP0[0][c][fr] + lredP0[1][c][fr]) + (lredP0[2][c][fr] + lredP0[3][c][fr]);
        p128t[c] = (lredP128[0][c][fr] + lredP128[1][c][fr]) + (lredP128[2][c][fr] + lredP128[3][c][fr]);
    }
    if (w == 0 && g == 0) {
#pragma unroll
        for (int c = 0; c < 4; ++c) {
            QW[c * 16 + fr][0]   = f2bf(p0t[c]);
            QW[c * 16 + fr][128] = f2bf(p128t[c]);
        }
    }
    __syncthreads();

    // ---- relv term (once): owner wave adds into its fd=w quarter ----
#pragma unroll
    for (int kc = 0; kc < 4; ++kc) {
        bf16x8 rv = *(const bf16x8*)&relvT[(size_t)(w * 16 + fr) * 136 + kc * 32 + g * 8];
#pragma unroll
        for (int c = 0; c < 4; ++c) {
            bf16x8 wa = *(const bf16x8*)&QW[c * 16 + fr][kc * 32 + g * 8];
            oacc[w][c] = __builtin_amdgcn_mfma_f32_16x16x32_bf16(rv, wa, oacc[w][c], 0, 0, 0);
        }
    }

    // ---- O cross-wave reduction (scratch = Klds), fd round-robin ----
    float* scr = (float*)&Klds[0][0][0];   // need 12 KB of the 24
    for (int fd = 0; fd < 4; ++fd) {
        if (w != fd) {
            const int sI = w - (w > fd ? 1 : 0);
#pragma unroll
            for (int c = 0; c < 4; ++c)
                *(f32x4*)&scr[(sI * 4 + c) * 256 + lane * 4] = oacc[fd][c];
        }
        __syncthreads();
        if (w == fd) {
#pragma unroll
            for (int c = 0; c < 4; ++c)
#pragma unroll
                for (int sI = 0; sI < 3; ++sI)
                    oacc[fd][c] += *(const f32x4*)&scr[(sI * 4 + c) * 256 + lane * 4];
        }
        __syncthreads();
    }

    // ---- owner wave writes its d-quarter for all 64 rows ----
    float r128[4];
#pragma unroll
    for (int reg = 0; reg < 4; ++reg)
        r128[reg] = relv[128 * 64 + w * 16 + g * 4 + reg];
#pragma unroll
    for (int c = 0; c < 4; ++c) {
        const float inv = 1.f / lt[c];
        float v0 = (oacc[w][c][0] + p128t[c] * r128[0]) * inv;
        float v1 = (oacc[w][c][1] + p128t[c] * r128[1]) * inv;
        float v2 = (oacc[w][c][2] + p128t[c] * r128[2]) * inv;
        float v3 = (oacc[w][c][3] + p128t[c] * r128[3]) * inv;
        unsigned long long pk = (unsigned long long)pk2bf(v0, v1)
                              | ((unsigned long long)pk2bf(v2, v3) << 32);
        *(unsigned long long*)&Ob[head + (size_t)(i0 + c * 16 + fr) * D_ + w * 16 + g * 4] = pk;
    }
}

// ------------------------------------------------------------------
extern "C" void kernel_launch(void* const* d_in, const int* in_sizes, int n_in,
                              void* d_out, int out_size, void* d_ws, size_t ws_size,
                              hipStream_t stream)
{
    const float* x    = (const float*)d_in[0];
    const float* Wq   = (const float*)d_in[1];
    const float* Wk   = (const float*)d_in[2];
    const float* Wv   = (const float*)d_in[3];
    const float* Wo   = (const float*)d_in[4];
    const float* relk = (const float*)d_in[5];
    const float* relv = (const float*)d_in[6];
    float* out = (float*)d_out;

    unsigned short* xb    = (unsigned short*)d_ws;
    unsigned short* Wt    = xb + NLD;
    unsigned short* relkb = Wt + 4 * DD;
    unsigned short* relvT = relkb + 144 * 64;
    unsigned short* QKVb  = relvT + 64 * 136;
    unsigned short* Ob    = QKVb + 3 * NLD;

    prep<<<dim3(6180), 256, 0, stream>>>(x, Wq, Wk, Wv, Wo, relk, relv, xb, Wt, relkb, relvT);

    gemm64<<<dim3(24, 32), 256, 0, stream>>>(xb, Wt, QKVb, nullptr, QSCALE);   // Q,K,V fused

    attn_mfma<<<dim3(512), 256, 0, stream>>>(QKVb, QKVb + NLD, QKVb + 2 * NLD,
                                             relkb, relvT, relv, Ob);

    gemm64<<<dim3(8, 32), 256, 0, stream>>>(Ob, Wt + 3 * DD, nullptr, out, 1.f);
}